// Round 5
// baseline (366.298 us; speedup 1.0000x reference)
//
#include <hip/hip_runtime.h>
#include <hip/hip_bf16.h>

#define BB 256
#define NIN 1024
#define NL 128
#define NSTEPS 256
#define MS 16384  // one 128x128 matrix slot (elements)

typedef __attribute__((ext_vector_type(8))) short bf16x8_t;
typedef __attribute__((ext_vector_type(4))) float f32x4_t;

__device__ inline unsigned short f2bf(float f) {
    __hip_bfloat16 h = __float2bfloat16(f);
    return *reinterpret_cast<unsigned short*>(&h);
}

// ---------------- K0: setup --------------------------------------------------
__global__ __launch_bounds__(128) void k_setup(const float* __restrict__ x,
                                               const float* __restrict__ tf,
                                               const float* __restrict__ tr,
                                               float* __restrict__ W,
                                               unsigned short* __restrict__ Wb,
                                               unsigned short* __restrict__ Fb,
                                               float* __restrict__ lat0,
                                               unsigned short* __restrict__ lat0b) {
    int t = threadIdx.x;
    if (blockIdx.x < 64) {
        __shared__ float xr[4][NIN];
        int b0 = blockIdx.x * 4;
#pragma unroll
        for (int rr = 0; rr < 4; ++rr) {
            const float4* xs = (const float4*)(x + (size_t)(b0 + rr) * NIN);
            for (int i = t; i < NIN / 4; i += 128) ((float4*)xr[rr])[i] = xs[i];
        }
        __syncthreads();
        float a0 = 0.f, a1 = 0.f, a2 = 0.f, a3 = 0.f;
#pragma unroll 8
        for (int i = 0; i < NIN; ++i) {
            float v = tf[i * NL + t];
            a0 += xr[0][i] * v; a1 += xr[1][i] * v;
            a2 += xr[2][i] * v; a3 += xr[3][i] * v;
        }
        lat0[(size_t)(b0 + 0) * NL + t] = a0;
        lat0[(size_t)(b0 + 1) * NL + t] = a1;
        lat0[(size_t)(b0 + 2) * NL + t] = a2;
        lat0[(size_t)(b0 + 3) * NL + t] = a3;
        lat0b[(size_t)(b0 + 0) * NL + t] = f2bf(a0);
        lat0b[(size_t)(b0 + 1) * NL + t] = f2bf(a1);
        lat0b[(size_t)(b0 + 2) * NL + t] = f2bf(a2);
        lat0b[(size_t)(b0 + 3) * NL + t] = f2bf(a3);
    } else {
        int id = (blockIdx.x - 64) * 128 + t;  // 0..8191
        for (int i = id; i < MS; i += 8192) {
            float v = tr[i];
            W[i] = v;
            Wb[i] = f2bf(v);
        }
        for (int i = id; i < NIN * NL; i += 8192) Fb[i] = f2bf(tf[i]);
    }
}

// ---------------- K1: power-chain level: D_i = A_i @ B (f32) ----------------
__global__ __launch_bounds__(256) void k_pmm(const float* __restrict__ A0,
                                             const float* __restrict__ Bm,
                                             float* __restrict__ D0,
                                             unsigned short* __restrict__ Db0) {
    int i = blockIdx.x >> 2, rt = blockIdx.x & 3;
    const float* A = A0 + (size_t)i * MS;
    float* D = D0 + (size_t)i * MS;
    unsigned short* Db = Db0 + (size_t)i * MS;
    int r0 = rt * 32;
    __shared__ float Bl[NL * NL];     // 64 KB
    __shared__ float At[NL][36];
    int t = threadIdx.x;
    for (int idx = t; idx < MS / 4; idx += 256)
        ((float4*)Bl)[idx] = ((const float4*)Bm)[idx];
    for (int idx = t; idx < 32 * NL; idx += 256) {
        int m = idx >> 7, kk = idx & 127;
        At[kk][m] = A[(size_t)(r0 + m) * NL + kk];
    }
    __syncthreads();
    int j = t & 127, rg = t >> 7;
    float acc[16];
#pragma unroll
    for (int q = 0; q < 16; ++q) acc[q] = 0.f;
#pragma unroll 2
    for (int kk = 0; kk < NL; ++kk) {
        float bv = Bl[kk * NL + j];
        const f32x4_t* ap = (const f32x4_t*)&At[kk][rg * 16];
        f32x4_t a0 = ap[0], a1 = ap[1], a2 = ap[2], a3 = ap[3];
        acc[0] += a0[0] * bv;  acc[1] += a0[1] * bv;
        acc[2] += a0[2] * bv;  acc[3] += a0[3] * bv;
        acc[4] += a1[0] * bv;  acc[5] += a1[1] * bv;
        acc[6] += a1[2] * bv;  acc[7] += a1[3] * bv;
        acc[8] += a2[0] * bv;  acc[9] += a2[1] * bv;
        acc[10] += a2[2] * bv; acc[11] += a2[3] * bv;
        acc[12] += a3[0] * bv; acc[13] += a3[1] * bv;
        acc[14] += a3[2] * bv; acc[15] += a3[3] * bv;
    }
#pragma unroll
    for (int q = 0; q < 16; ++q) {
        size_t off = (size_t)(r0 + rg * 16 + q) * NL + j;
        D[off] = acc[q];
        Db[off] = f2bf(acc[q]);
    }
}

// ---------------- K2: G[(n*256+s)][m] = bf16(sum_l F[n,l] * T^{s+1}[m,l]) --
__global__ __launch_bounds__(256) void k_G(const unsigned short* __restrict__ Fb,
                                           const unsigned short* __restrict__ Wb,
                                           unsigned short* __restrict__ G) {
    int s = blockIdx.x >> 3;
    int nt = blockIdx.x & 7;
    __shared__ __align__(16) char lA[128 * 256];
    __shared__ __align__(16) char lB[128 * 256];
    int t = threadIdx.x;
    const unsigned short* Ag = Fb + (size_t)(nt * 128) * NL;
    const unsigned short* Bg = Wb + (size_t)s * MS;
    for (int i = t; i < 2048; i += 256) {
        int row = i >> 4, c = i & 15;
        int sw = (c * 16) ^ ((row & 7) << 4);
        *(bf16x8_t*)(lA + row * 256 + sw) =
            *(const bf16x8_t*)(Ag + (size_t)row * NL + c * 8);
        *(bf16x8_t*)(lB + row * 256 + sw) =
            *(const bf16x8_t*)(Bg + (size_t)row * NL + c * 8);
    }
    __syncthreads();
    int w = t >> 6, lane = t & 63;
    int wn = (w >> 1) * 64;
    int wm = (w & 1) * 64;
    int r = lane & 15, g = lane >> 4;
    f32x4_t acc[4][4];
#pragma unroll
    for (int mf = 0; mf < 4; ++mf)
#pragma unroll
        for (int nf = 0; nf < 4; ++nf) acc[mf][nf] = (f32x4_t){0.f, 0.f, 0.f, 0.f};
#pragma unroll
    for (int kk = 0; kk < 4; ++kk) {
        int c16 = kk * 4 + g;
        bf16x8_t av[4], bv[4];
#pragma unroll
        for (int mf = 0; mf < 4; ++mf) {
            int rowA = wn + mf * 16 + r;
            av[mf] = *(const bf16x8_t*)(lA + rowA * 256 + ((c16 * 16) ^ ((rowA & 7) << 4)));
            int rowB = wm + mf * 16 + r;
            bv[mf] = *(const bf16x8_t*)(lB + rowB * 256 + ((c16 * 16) ^ ((rowB & 7) << 4)));
        }
#pragma unroll
        for (int mf = 0; mf < 4; ++mf)
#pragma unroll
            for (int nf = 0; nf < 4; ++nf)
                acc[mf][nf] = __builtin_amdgcn_mfma_f32_16x16x32_bf16(av[mf], bv[nf], acc[mf][nf], 0, 0, 0);
    }
#pragma unroll
    for (int mf = 0; mf < 4; ++mf) {
#pragma unroll
        for (int nf = 0; nf < 4; ++nf) {
#pragma unroll
            for (int q = 0; q < 4; ++q) {
                int n_row = nt * 128 + wn + mf * 16 + g * 4 + q;
                int mcol = wm + nf * 16 + r;
                G[((size_t)n_row * NSTEPS + s) * NL + mcol] = f2bf(acc[mf][nf][q]);
            }
        }
    }
}

// ---------------- K3: out = lat0b @ G^T (direct stores, bt-loop) -----------
// grid = ct(2048); 32 KB LDS -> high occupancy; launched TWICE (calibration).
__global__ __launch_bounds__(256) void k_main(const unsigned short* __restrict__ lat0b,
                                              const unsigned short* __restrict__ G,
                                              float* __restrict__ out) {
    int ct = blockIdx.x;
    __shared__ __align__(16) char lB[128 * 256];   // swizzled G tile (32 KB)
    int t = threadIdx.x;
    const unsigned short* Bg = G + (size_t)ct * 128 * NL;
    for (int i = t; i < 2048; i += 256) {
        int row = i >> 4, c = i & 15;
        int sw = (c * 16) ^ ((row & 7) << 4);
        *(bf16x8_t*)(lB + row * 256 + sw) =
            *(const bf16x8_t*)(Bg + (size_t)row * NL + c * 8);
    }
    __syncthreads();
    int w = t >> 6, lane = t & 63;
    int wr = (w >> 1) * 64;   // wave b-row offset
    int wc = (w & 1) * 64;    // wave col offset
    int r = lane & 15, g = lane >> 4;

    for (int bt = 0; bt < 2; ++bt) {
        const unsigned short* Arow = lat0b + (size_t)(bt * 128) * NL;
        bf16x8_t av[4][4];  // [kk][mf]
#pragma unroll
        for (int kk = 0; kk < 4; ++kk) {
            int c16 = kk * 4 + g;
#pragma unroll
            for (int mf = 0; mf < 4; ++mf)
                av[kk][mf] = *(const bf16x8_t*)(Arow + (size_t)(wr + mf * 16 + r) * NL + c16 * 8);
        }
        f32x4_t acc[4][4];
#pragma unroll
        for (int mf = 0; mf < 4; ++mf)
#pragma unroll
            for (int nf = 0; nf < 4; ++nf) acc[mf][nf] = (f32x4_t){0.f, 0.f, 0.f, 0.f};
#pragma unroll
        for (int kk = 0; kk < 4; ++kk) {
            int c16 = kk * 4 + g;
            bf16x8_t bv[4];
#pragma unroll
            for (int nf = 0; nf < 4; ++nf) {
                int rowB = wc + nf * 16 + r;
                bv[nf] = *(const bf16x8_t*)(lB + rowB * 256 + ((c16 * 16) ^ ((rowB & 7) << 4)));
            }
#pragma unroll
            for (int mf = 0; mf < 4; ++mf)
#pragma unroll
                for (int nf = 0; nf < 4; ++nf)
                    acc[mf][nf] = __builtin_amdgcn_mfma_f32_16x16x32_bf16(av[kk][mf], bv[nf], acc[mf][nf], 0, 0, 0);
        }
#pragma unroll
        for (int mf = 0; mf < 4; ++mf) {
#pragma unroll
            for (int nf = 0; nf < 4; ++nf) {
#pragma unroll
                for (int q = 0; q < 4; ++q) {
                    int brow = bt * 128 + wr + mf * 16 + g * 4 + q;
                    int col = ct * 128 + wc + nf * 16 + r;
                    out[(size_t)brow * (NIN * NSTEPS) + col] = acc[mf][nf][q];
                }
            }
        }
    }
}

extern "C" void kernel_launch(void* const* d_in, const int* in_sizes, int n_in,
                              void* d_out, int out_size, void* d_ws, size_t ws_size,
                              hipStream_t stream) {
    const float* x = (const float*)d_in[0];
    const float* tf = (const float*)d_in[1];
    const float* tr = (const float*)d_in[2];
    float* out = (float*)d_out;

    float* W = (float*)d_ws;                         // 256 slots f32: T^1..T^256
    float* lat0 = W + (size_t)256 * MS;
    unsigned short* Wb = (unsigned short*)(lat0 + (size_t)BB * NL);
    unsigned short* Fb = Wb + (size_t)256 * MS;
    unsigned short* lat0b = Fb + (size_t)NIN * NL;
    unsigned short* G = lat0b + (size_t)BB * NL;     // [262144][128] bf16 (67 MB)

    k_setup<<<128, 128, 0, stream>>>(x, tf, tr, W, Wb, Fb, lat0, lat0b);

    for (int m = 1; m <= 128; m <<= 1) {
        k_pmm<<<m * 4, 256, 0, stream>>>(W, W + (size_t)(m - 1) * MS,
                                         W + (size_t)m * MS, Wb + (size_t)m * MS);
    }

    k_G<<<2048, 256, 0, stream>>>(Fb, Wb, G);
    // CALIBRATION: k_main launched twice with identical args (idempotent).
    // dur_R5 - dur_R4 ~= one k_main duration.
    k_main<<<2048, 256, 0, stream>>>(lat0b, G, out);
    k_main<<<2048, 256, 0, stream>>>(lat0b, G, out);
}

// Round 6
// 261.559 us; speedup vs baseline: 1.4004x; 1.4004x over previous
//
#include <hip/hip_runtime.h>
#include <hip/hip_bf16.h>

#define BB 256
#define NIN 1024
#define NL 128
#define NSTEPS 256
#define MS 16384  // one 128x128 matrix slot (elements)

typedef __attribute__((ext_vector_type(8))) short bf16x8_t;
typedef __attribute__((ext_vector_type(4))) float f32x4_t;

__device__ inline unsigned short f2bf(float f) {
    __hip_bfloat16 h = __float2bfloat16(f);
    return *reinterpret_cast<unsigned short*>(&h);
}

// ---------------- K0: setup --------------------------------------------------
__global__ __launch_bounds__(128) void k_setup(const float* __restrict__ x,
                                               const float* __restrict__ tf,
                                               const float* __restrict__ tr,
                                               float* __restrict__ W,
                                               unsigned short* __restrict__ Wb,
                                               unsigned short* __restrict__ Fb,
                                               float* __restrict__ lat0,
                                               unsigned short* __restrict__ lat0b) {
    int t = threadIdx.x;
    if (blockIdx.x < 64) {
        __shared__ float xr[4][NIN];
        int b0 = blockIdx.x * 4;
#pragma unroll
        for (int rr = 0; rr < 4; ++rr) {
            const float4* xs = (const float4*)(x + (size_t)(b0 + rr) * NIN);
            for (int i = t; i < NIN / 4; i += 128) ((float4*)xr[rr])[i] = xs[i];
        }
        __syncthreads();
        float a0 = 0.f, a1 = 0.f, a2 = 0.f, a3 = 0.f;
#pragma unroll 8
        for (int i = 0; i < NIN; ++i) {
            float v = tf[i * NL + t];
            a0 += xr[0][i] * v; a1 += xr[1][i] * v;
            a2 += xr[2][i] * v; a3 += xr[3][i] * v;
        }
        lat0[(size_t)(b0 + 0) * NL + t] = a0;
        lat0[(size_t)(b0 + 1) * NL + t] = a1;
        lat0[(size_t)(b0 + 2) * NL + t] = a2;
        lat0[(size_t)(b0 + 3) * NL + t] = a3;
        lat0b[(size_t)(b0 + 0) * NL + t] = f2bf(a0);
        lat0b[(size_t)(b0 + 1) * NL + t] = f2bf(a1);
        lat0b[(size_t)(b0 + 2) * NL + t] = f2bf(a2);
        lat0b[(size_t)(b0 + 3) * NL + t] = f2bf(a3);
    } else {
        int id = (blockIdx.x - 64) * 128 + t;  // 0..8191
        for (int i = id; i < MS; i += 8192) {
            float v = tr[i];
            W[i] = v;
            Wb[i] = f2bf(v);
        }
        for (int i = id; i < NIN * NL; i += 8192) Fb[i] = f2bf(tf[i]);
    }
}

// ---------------- K1: power-chain level: D_i = A_i @ B (f32) ----------------
__global__ __launch_bounds__(256) void k_pmm(const float* __restrict__ A0,
                                             const float* __restrict__ Bm,
                                             float* __restrict__ D0,
                                             unsigned short* __restrict__ Db0) {
    int i = blockIdx.x >> 2, rt = blockIdx.x & 3;
    const float* A = A0 + (size_t)i * MS;
    float* D = D0 + (size_t)i * MS;
    unsigned short* Db = Db0 + (size_t)i * MS;
    int r0 = rt * 32;
    __shared__ float Bl[NL * NL];     // 64 KB
    __shared__ float At[NL][36];
    int t = threadIdx.x;
    for (int idx = t; idx < MS / 4; idx += 256)
        ((float4*)Bl)[idx] = ((const float4*)Bm)[idx];
    for (int idx = t; idx < 32 * NL; idx += 256) {
        int m = idx >> 7, kk = idx & 127;
        At[kk][m] = A[(size_t)(r0 + m) * NL + kk];
    }
    __syncthreads();
    int j = t & 127, rg = t >> 7;
    float acc[16];
#pragma unroll
    for (int q = 0; q < 16; ++q) acc[q] = 0.f;
#pragma unroll 2
    for (int kk = 0; kk < NL; ++kk) {
        float bv = Bl[kk * NL + j];
        const f32x4_t* ap = (const f32x4_t*)&At[kk][rg * 16];
        f32x4_t a0 = ap[0], a1 = ap[1], a2 = ap[2], a3 = ap[3];
        acc[0] += a0[0] * bv;  acc[1] += a0[1] * bv;
        acc[2] += a0[2] * bv;  acc[3] += a0[3] * bv;
        acc[4] += a1[0] * bv;  acc[5] += a1[1] * bv;
        acc[6] += a1[2] * bv;  acc[7] += a1[3] * bv;
        acc[8] += a2[0] * bv;  acc[9] += a2[1] * bv;
        acc[10] += a2[2] * bv; acc[11] += a2[3] * bv;
        acc[12] += a3[0] * bv; acc[13] += a3[1] * bv;
        acc[14] += a3[2] * bv; acc[15] += a3[3] * bv;
    }
#pragma unroll
    for (int q = 0; q < 16; ++q) {
        size_t off = (size_t)(r0 + rg * 16 + q) * NL + j;
        D[off] = acc[q];
        Db[off] = f2bf(acc[q]);
    }
}

// ---------------- K2: Gs[s][n][m] = bf16(sum_l F[n,l] * T^{s+1}[m,l]) -------
// s-major layout: block writes 32 KB CONTIGUOUS. Swapped-operand MFMA ->
// lane holds 4 consecutive m -> 8B packed stores. XCD-chunked swizzle.
__global__ __launch_bounds__(256) void k_G(const unsigned short* __restrict__ Fb,
                                           const unsigned short* __restrict__ Wb,
                                           unsigned short* __restrict__ Gs) {
    int bid = blockIdx.x;
    int e = ((bid & 7) << 8) | (bid >> 3);  // XCD gets contiguous range
    int s = e >> 3;
    int nt = e & 7;
    __shared__ __align__(16) char lA[128 * 256];  // Fb tile (n-rows)
    __shared__ __align__(16) char lB[128 * 256];  // Wb tile (m-rows)
    int t = threadIdx.x;
    const unsigned short* Ag = Fb + (size_t)(nt * 128) * NL;
    const unsigned short* Bg = Wb + (size_t)s * MS;
    for (int i = t; i < 2048; i += 256) {
        int row = i >> 4, c = i & 15;
        int sw = (c * 16) ^ ((row & 7) << 4);
        *(bf16x8_t*)(lA + row * 256 + sw) =
            *(const bf16x8_t*)(Ag + (size_t)row * NL + c * 8);
        *(bf16x8_t*)(lB + row * 256 + sw) =
            *(const bf16x8_t*)(Bg + (size_t)row * NL + c * 8);
    }
    __syncthreads();
    int w = t >> 6, lane = t & 63;
    int wn = (w >> 1) * 64;
    int wm = (w & 1) * 64;
    int r = lane & 15, g = lane >> 4;
    f32x4_t acc[4][4];  // [a = n-frag][b = m-frag]
#pragma unroll
    for (int a = 0; a < 4; ++a)
#pragma unroll
        for (int b = 0; b < 4; ++b) acc[a][b] = (f32x4_t){0.f, 0.f, 0.f, 0.f};
#pragma unroll
    for (int kk = 0; kk < 4; ++kk) {
        int c16 = kk * 4 + g;
        bf16x8_t av[4], bv[4];
#pragma unroll
        for (int a = 0; a < 4; ++a) {
            int rowA = wn + a * 16 + r;
            av[a] = *(const bf16x8_t*)(lA + rowA * 256 + ((c16 * 16) ^ ((rowA & 7) << 4)));
            int rowB = wm + a * 16 + r;
            bv[a] = *(const bf16x8_t*)(lB + rowB * 256 + ((c16 * 16) ^ ((rowB & 7) << 4)));
        }
        // swapped: A-operand = bv (m-rows) -> reg dim = m; lane&15 = n
#pragma unroll
        for (int a = 0; a < 4; ++a)
#pragma unroll
            for (int b = 0; b < 4; ++b)
                acc[a][b] = __builtin_amdgcn_mfma_f32_16x16x32_bf16(bv[b], av[a], acc[a][b], 0, 0, 0);
    }
#pragma unroll
    for (int a = 0; a < 4; ++a) {
        int n = nt * 128 + wn + a * 16 + r;
#pragma unroll
        for (int b = 0; b < 4; ++b) {
            int m0 = wm + b * 16 + g * 4;
            ushort4 o;
            o.x = f2bf(acc[a][b][0]); o.y = f2bf(acc[a][b][1]);
            o.z = f2bf(acc[a][b][2]); o.w = f2bf(acc[a][b][3]);
            *(ushort4*)&Gs[((size_t)s * NIN + n) * NL + m0] = o;
        }
    }
}

// ---------------- K3: out = lat0b @ Gs^T -----------------------------------
// grid ct(2048) XCD-chunk-swizzled; bt looped (Gs tile read once); swapped
// MFMA -> dwordx4 f32 stores of 4 consecutive out-cols.
__global__ __launch_bounds__(256) void k_main(const unsigned short* __restrict__ lat0b,
                                              const unsigned short* __restrict__ Gs,
                                              float* __restrict__ out) {
    int bid = blockIdx.x;
    int ct = ((bid & 7) << 8) | (bid >> 3);  // XCD gets contiguous ct span
    int n0 = ct >> 1;
    int s0 = (ct & 1) * 128;
    __shared__ __align__(16) char lB[128 * 256];   // swizzled G tile (32 KB)
    int t = threadIdx.x;
    // stage: local row i = (n,s) pair ct*128+i -> Gs row (s0+i, n0)
    for (int i = t; i < 2048; i += 256) {
        int row = i >> 4, c = i & 15;
        int sw = (c * 16) ^ ((row & 7) << 4);
        *(bf16x8_t*)(lB + row * 256 + sw) =
            *(const bf16x8_t*)(Gs + ((size_t)(s0 + row) * NIN + n0) * NL + c * 8);
    }
    __syncthreads();
    int w = t >> 6, lane = t & 63;
    int wr = (w >> 1) * 64;   // wave b-row offset
    int wc = (w & 1) * 64;    // wave col offset
    int r = lane & 15, g = lane >> 4;

    for (int bt = 0; bt < 2; ++bt) {
        const unsigned short* Arow = lat0b + (size_t)(bt * 128) * NL;
        bf16x8_t av[4][4];  // [kk][mf]
#pragma unroll
        for (int kk = 0; kk < 4; ++kk) {
            int c16 = kk * 4 + g;
#pragma unroll
            for (int mf = 0; mf < 4; ++mf)
                av[kk][mf] = *(const bf16x8_t*)(Arow + (size_t)(wr + mf * 16 + r) * NL + c16 * 8);
        }
        f32x4_t acc[4][4];  // [mf][nf]; reg dim = col, lane&15 = b-row
#pragma unroll
        for (int mf = 0; mf < 4; ++mf)
#pragma unroll
            for (int nf = 0; nf < 4; ++nf) acc[mf][nf] = (f32x4_t){0.f, 0.f, 0.f, 0.f};
#pragma unroll
        for (int kk = 0; kk < 4; ++kk) {
            int c16 = kk * 4 + g;
            bf16x8_t bv[4];
#pragma unroll
            for (int nf = 0; nf < 4; ++nf) {
                int rowB = wc + nf * 16 + r;
                bv[nf] = *(const bf16x8_t*)(lB + rowB * 256 + ((c16 * 16) ^ ((rowB & 7) << 4)));
            }
            // swapped: A-operand = bv (col rows) -> reg dim = col
#pragma unroll
            for (int mf = 0; mf < 4; ++mf)
#pragma unroll
                for (int nf = 0; nf < 4; ++nf)
                    acc[mf][nf] = __builtin_amdgcn_mfma_f32_16x16x32_bf16(bv[nf], av[kk][mf], acc[mf][nf], 0, 0, 0);
        }
#pragma unroll
        for (int mf = 0; mf < 4; ++mf) {
            int brow = bt * 128 + wr + mf * 16 + r;
#pragma unroll
            for (int nf = 0; nf < 4; ++nf) {
                int col0 = ct * 128 + wc + nf * 16 + g * 4;
                *(f32x4_t*)&out[(size_t)brow * (NIN * NSTEPS) + col0] = acc[mf][nf];
            }
        }
    }
}

extern "C" void kernel_launch(void* const* d_in, const int* in_sizes, int n_in,
                              void* d_out, int out_size, void* d_ws, size_t ws_size,
                              hipStream_t stream) {
    const float* x = (const float*)d_in[0];
    const float* tf = (const float*)d_in[1];
    const float* tr = (const float*)d_in[2];
    float* out = (float*)d_out;

    float* W = (float*)d_ws;                         // 256 slots f32: T^1..T^256
    float* lat0 = W + (size_t)256 * MS;
    unsigned short* Wb = (unsigned short*)(lat0 + (size_t)BB * NL);
    unsigned short* Fb = Wb + (size_t)256 * MS;
    unsigned short* lat0b = Fb + (size_t)NIN * NL;
    unsigned short* Gs = lat0b + (size_t)BB * NL;    // [s=256][n=1024][m=128] bf16

    k_setup<<<128, 128, 0, stream>>>(x, tf, tr, W, Wb, Fb, lat0, lat0b);

    for (int m = 1; m <= 128; m <<= 1) {
        k_pmm<<<m * 4, 256, 0, stream>>>(W, W + (size_t)(m - 1) * MS,
                                         W + (size_t)m * MS, Wb + (size_t)m * MS);
    }

    k_G<<<2048, 256, 0, stream>>>(Fb, Wb, Gs);
    k_main<<<2048, 256, 0, stream>>>(lat0b, Gs, out);
}

// Round 7
// 224.872 us; speedup vs baseline: 1.6289x; 1.1631x over previous
//
#include <hip/hip_runtime.h>
#include <hip/hip_bf16.h>

#define BB 256
#define NIN 1024
#define NL 128
#define NSTEPS 256
#define MS 16384  // one 128x128 matrix slot (elements)

typedef __attribute__((ext_vector_type(8))) short bf16x8_t;
typedef __attribute__((ext_vector_type(4))) float f32x4_t;

__device__ inline unsigned short f2bf(float f) {
    __hip_bfloat16 h = __float2bfloat16(f);
    return *reinterpret_cast<unsigned short*>(&h);
}

// ---------------- K0: setup --------------------------------------------------
__global__ __launch_bounds__(128) void k_setup(const float* __restrict__ x,
                                               const float* __restrict__ tf,
                                               const float* __restrict__ tr,
                                               float* __restrict__ W,
                                               unsigned short* __restrict__ Wb,
                                               unsigned short* __restrict__ Fb,
                                               float* __restrict__ lat0,
                                               unsigned short* __restrict__ lat0b) {
    int t = threadIdx.x;
    if (blockIdx.x < 64) {
        __shared__ float xr[4][NIN];
        int b0 = blockIdx.x * 4;
#pragma unroll
        for (int rr = 0; rr < 4; ++rr) {
            const float4* xs = (const float4*)(x + (size_t)(b0 + rr) * NIN);
            for (int i = t; i < NIN / 4; i += 128) ((float4*)xr[rr])[i] = xs[i];
        }
        __syncthreads();
        float a0 = 0.f, a1 = 0.f, a2 = 0.f, a3 = 0.f;
#pragma unroll 8
        for (int i = 0; i < NIN; ++i) {
            float v = tf[i * NL + t];
            a0 += xr[0][i] * v; a1 += xr[1][i] * v;
            a2 += xr[2][i] * v; a3 += xr[3][i] * v;
        }
        lat0[(size_t)(b0 + 0) * NL + t] = a0;
        lat0[(size_t)(b0 + 1) * NL + t] = a1;
        lat0[(size_t)(b0 + 2) * NL + t] = a2;
        lat0[(size_t)(b0 + 3) * NL + t] = a3;
        lat0b[(size_t)(b0 + 0) * NL + t] = f2bf(a0);
        lat0b[(size_t)(b0 + 1) * NL + t] = f2bf(a1);
        lat0b[(size_t)(b0 + 2) * NL + t] = f2bf(a2);
        lat0b[(size_t)(b0 + 3) * NL + t] = f2bf(a3);
    } else {
        int id = (blockIdx.x - 64) * 128 + t;  // 0..8191
        for (int i = id; i < MS; i += 8192) {
            float v = tr[i];
            W[i] = v;
            Wb[i] = f2bf(v);
        }
        for (int i = id; i < NIN * NL; i += 8192) Fb[i] = f2bf(tf[i]);
    }
}

// ---------------- K1: power-chain level: D_i = A_i @ B (f32), slim ----------
// block computes 32 rows x 64 cols; LDS 50KB -> 3 blocks/CU; grid = 8*nmat.
__global__ __launch_bounds__(256) void k_pmm(const float* __restrict__ A0,
                                             const float* __restrict__ Bm,
                                             float* __restrict__ D0,
                                             unsigned short* __restrict__ Db0) {
    int i = blockIdx.x >> 3, rt = (blockIdx.x >> 1) & 3, jt = blockIdx.x & 1;
    const float* A = A0 + (size_t)i * MS;
    float* D = D0 + (size_t)i * MS;
    unsigned short* Db = Db0 + (size_t)i * MS;
    int r0 = rt * 32, j0 = jt * 64;
    __shared__ float Bl[NL * 64];     // 32 KB (cols j0..j0+64)
    __shared__ float At[NL][36];      // 18 KB
    int t = threadIdx.x;
    for (int idx = t; idx < NL * 16; idx += 256) {
        int row = idx >> 4, c = idx & 15;
        *(float4*)&Bl[row * 64 + c * 4] = *(const float4*)&Bm[row * NL + j0 + c * 4];
    }
    for (int idx = t; idx < 32 * NL; idx += 256) {
        int m = idx >> 7, kk = idx & 127;
        At[kk][m] = A[(size_t)(r0 + m) * NL + kk];
    }
    __syncthreads();
    int j = t & 63, rg = t >> 6;  // rg in 0..3, 8 rows each
    float acc[8];
#pragma unroll
    for (int q = 0; q < 8; ++q) acc[q] = 0.f;
#pragma unroll 4
    for (int kk = 0; kk < NL; ++kk) {
        float bv = Bl[kk * 64 + j];
        const f32x4_t* ap = (const f32x4_t*)&At[kk][rg * 8];
        f32x4_t a0 = ap[0], a1 = ap[1];
        acc[0] += a0[0] * bv;  acc[1] += a0[1] * bv;
        acc[2] += a0[2] * bv;  acc[3] += a0[3] * bv;
        acc[4] += a1[0] * bv;  acc[5] += a1[1] * bv;
        acc[6] += a1[2] * bv;  acc[7] += a1[3] * bv;
    }
#pragma unroll
    for (int q = 0; q < 8; ++q) {
        size_t off = (size_t)(r0 + rg * 8 + q) * NL + j0 + j;
        D[off] = acc[q];
        Db[off] = f2bf(acc[q]);
    }
}

// ---------------- K2: Gs[s][n][m] = bf16(sum_l F[n,l] * T^{s+1}[m,l]) -------
__global__ __launch_bounds__(256) void k_G(const unsigned short* __restrict__ Fb,
                                           const unsigned short* __restrict__ Wb,
                                           unsigned short* __restrict__ Gs) {
    int bid = blockIdx.x;
    int e = ((bid & 7) << 8) | (bid >> 3);  // XCD gets contiguous range
    int s = e >> 3;
    int nt = e & 7;
    __shared__ __align__(16) char lA[128 * 256];  // Fb tile (n-rows)
    __shared__ __align__(16) char lB[128 * 256];  // Wb tile (m-rows)
    int t = threadIdx.x;
    const unsigned short* Ag = Fb + (size_t)(nt * 128) * NL;
    const unsigned short* Bg = Wb + (size_t)s * MS;
    for (int i = t; i < 2048; i += 256) {
        int row = i >> 4, c = i & 15;
        int sw = (c * 16) ^ ((row & 7) << 4);
        *(bf16x8_t*)(lA + row * 256 + sw) =
            *(const bf16x8_t*)(Ag + (size_t)row * NL + c * 8);
        *(bf16x8_t*)(lB + row * 256 + sw) =
            *(const bf16x8_t*)(Bg + (size_t)row * NL + c * 8);
    }
    __syncthreads();
    int w = t >> 6, lane = t & 63;
    int wn = (w >> 1) * 64;
    int wm = (w & 1) * 64;
    int r = lane & 15, g = lane >> 4;
    f32x4_t acc[4][4];  // [a = n-frag][b = m-frag]
#pragma unroll
    for (int a = 0; a < 4; ++a)
#pragma unroll
        for (int b = 0; b < 4; ++b) acc[a][b] = (f32x4_t){0.f, 0.f, 0.f, 0.f};
#pragma unroll
    for (int kk = 0; kk < 4; ++kk) {
        int c16 = kk * 4 + g;
        bf16x8_t av[4], bv[4];
#pragma unroll
        for (int a = 0; a < 4; ++a) {
            int rowA = wn + a * 16 + r;
            av[a] = *(const bf16x8_t*)(lA + rowA * 256 + ((c16 * 16) ^ ((rowA & 7) << 4)));
            int rowB = wm + a * 16 + r;
            bv[a] = *(const bf16x8_t*)(lB + rowB * 256 + ((c16 * 16) ^ ((rowB & 7) << 4)));
        }
#pragma unroll
        for (int a = 0; a < 4; ++a)
#pragma unroll
            for (int b = 0; b < 4; ++b)
                acc[a][b] = __builtin_amdgcn_mfma_f32_16x16x32_bf16(bv[b], av[a], acc[a][b], 0, 0, 0);
    }
#pragma unroll
    for (int a = 0; a < 4; ++a) {
        int n = nt * 128 + wn + a * 16 + r;
#pragma unroll
        for (int b = 0; b < 4; ++b) {
            int m0 = wm + b * 16 + g * 4;
            ushort4 o;
            o.x = f2bf(acc[a][b][0]); o.y = f2bf(acc[a][b][1]);
            o.z = f2bf(acc[a][b][2]); o.w = f2bf(acc[a][b][3]);
            *(ushort4*)&Gs[((size_t)s * NIN + n) * NL + m0] = o;
        }
    }
}

// ---------------- K3: out = lat0b @ Gs^T — NONTEMPORAL stores --------------
__global__ __launch_bounds__(256) void k_main(const unsigned short* __restrict__ lat0b,
                                              const unsigned short* __restrict__ Gs,
                                              float* __restrict__ out) {
    int bid = blockIdx.x;
    int ct = ((bid & 7) << 8) | (bid >> 3);  // XCD gets contiguous ct span
    int n0 = ct >> 1;
    int s0 = (ct & 1) * 128;
    __shared__ __align__(16) char lB[128 * 256];   // swizzled G tile (32 KB)
    int t = threadIdx.x;
    for (int i = t; i < 2048; i += 256) {
        int row = i >> 4, c = i & 15;
        int sw = (c * 16) ^ ((row & 7) << 4);
        *(bf16x8_t*)(lB + row * 256 + sw) =
            *(const bf16x8_t*)(Gs + ((size_t)(s0 + row) * NIN + n0) * NL + c * 8);
    }
    __syncthreads();
    int w = t >> 6, lane = t & 63;
    int wr = (w >> 1) * 64;   // wave b-row offset
    int wc = (w & 1) * 64;    // wave col offset
    int r = lane & 15, g = lane >> 4;

    for (int bt = 0; bt < 2; ++bt) {
        const unsigned short* Arow = lat0b + (size_t)(bt * 128) * NL;
        bf16x8_t av[4][4];  // [kk][mf]
#pragma unroll
        for (int kk = 0; kk < 4; ++kk) {
            int c16 = kk * 4 + g;
#pragma unroll
            for (int mf = 0; mf < 4; ++mf)
                av[kk][mf] = *(const bf16x8_t*)(Arow + (size_t)(wr + mf * 16 + r) * NL + c16 * 8);
        }
        f32x4_t acc[4][4];  // [mf][nf]; reg dim = col, lane&15 = b-row
#pragma unroll
        for (int mf = 0; mf < 4; ++mf)
#pragma unroll
            for (int nf = 0; nf < 4; ++nf) acc[mf][nf] = (f32x4_t){0.f, 0.f, 0.f, 0.f};
#pragma unroll
        for (int kk = 0; kk < 4; ++kk) {
            int c16 = kk * 4 + g;
            bf16x8_t bv[4];
#pragma unroll
            for (int nf = 0; nf < 4; ++nf) {
                int rowB = wc + nf * 16 + r;
                bv[nf] = *(const bf16x8_t*)(lB + rowB * 256 + ((c16 * 16) ^ ((rowB & 7) << 4)));
            }
#pragma unroll
            for (int mf = 0; mf < 4; ++mf)
#pragma unroll
                for (int nf = 0; nf < 4; ++nf)
                    acc[mf][nf] = __builtin_amdgcn_mfma_f32_16x16x32_bf16(bv[nf], av[kk][mf], acc[mf][nf], 0, 0, 0);
        }
#pragma unroll
        for (int mf = 0; mf < 4; ++mf) {
            int brow = bt * 128 + wr + mf * 16 + r;
#pragma unroll
            for (int nf = 0; nf < 4; ++nf) {
                int col0 = ct * 128 + wc + nf * 16 + g * 4;
                __builtin_nontemporal_store(
                    acc[mf][nf],
                    (f32x4_t*)&out[(size_t)brow * (NIN * NSTEPS) + col0]);
            }
        }
    }
}

extern "C" void kernel_launch(void* const* d_in, const int* in_sizes, int n_in,
                              void* d_out, int out_size, void* d_ws, size_t ws_size,
                              hipStream_t stream) {
    const float* x = (const float*)d_in[0];
    const float* tf = (const float*)d_in[1];
    const float* tr = (const float*)d_in[2];
    float* out = (float*)d_out;

    float* W = (float*)d_ws;                         // 256 slots f32: T^1..T^256
    float* lat0 = W + (size_t)256 * MS;
    unsigned short* Wb = (unsigned short*)(lat0 + (size_t)BB * NL);
    unsigned short* Fb = Wb + (size_t)256 * MS;
    unsigned short* lat0b = Fb + (size_t)NIN * NL;
    unsigned short* Gs = lat0b + (size_t)BB * NL;    // [s=256][n=1024][m=128] bf16

    k_setup<<<128, 128, 0, stream>>>(x, tf, tr, W, Wb, Fb, lat0, lat0b);

    for (int m = 1; m <= 128; m <<= 1) {
        k_pmm<<<m * 8, 256, 0, stream>>>(W, W + (size_t)(m - 1) * MS,
                                         W + (size_t)m * MS, Wb + (size_t)m * MS);
    }

    k_G<<<2048, 256, 0, stream>>>(Fb, Wb, Gs);
    k_main<<<2048, 256, 0, stream>>>(lat0b, Gs, out);
}